// Round 2
// 69.482 us; speedup vs baseline: 1.1009x; 1.1009x over previous
//
#include <hip/hip_runtime.h>
#include <math.h>

// MeshfreeKANNet: out[m] = sum_n phi(m,n) * w[n]
//   phi = windowed+normalized softplus(KAN(diff/radius)), cubic window radius 0.06
//   orphan rows (phi_sum < 1e-14) fall back to exp-weighted 8-NN.
//
// R3 restructure: ONE WAVE PER ROW (4 rows / 256-thread block, grid = M/4).
// Rationale (from R2 post-mortem): R2's one-block-per-row had a ~4 us serial
// critical path per block (stage+barrier -> atomicAdd compaction -> barrier ->
// wave-0-only KAN while 3 waves idle -> block reduce) and 3 inlined kan_phi
// copies inflating VGPRs; blocks executed near-serially -> ~36 us kernel.
// Here: no barriers after weight staging, no LDS atomics, no idle waves,
// register compaction counter, fallback recomputes d2 (no dloc[8] cache).
// R4: identical resubmit — R3 bench was an MI355X container infra failure
// (no counters, no pass/fail); kernel audited clean for hangs/faults.

#define RADIUS 0.06f
#define INV_RADIUS (1.0f / 0.06f)
#define R2 (0.06f * 0.06f)
#define INV_H (4.0f / 3.0f)   // 1/h, h = 0.75
#define CAP 256               // per-wave compaction capacity (expected ~23)

__device__ __forceinline__ float hatf(float x, float g) {
    return fmaxf(1.0f - fabsf(x - g) * INV_H, 0.0f);
}

// softplus(KAN(dx/r, dy/r)) * cubic_window(sqrt(d2)/r)
__device__ __forceinline__ float kan_phi(float dx, float dy, float d2,
                                         const float* __restrict__ s_w1a,
                                         const float* __restrict__ s_w1b,
                                         const float* __restrict__ s_w2) {
    const float u = dx * INV_RADIUS;
    const float v = dy * INV_RADIUS;
    float b0[5], b1[5];
    #pragma unroll
    for (int i = 0; i < 5; ++i) {
        const float g = -1.5f + 0.75f * (float)i;
        b0[i] = hatf(u, g);
        b1[i] = hatf(v, g);
    }
    float o = 0.0f;
    #pragma unroll
    for (int j = 0; j < 8; ++j) {
        float hj = 0.0f;
        #pragma unroll
        for (int i = 0; i < 5; ++i)
            hj += b0[i] * s_w1a[j * 5 + i] + b1[i] * s_w1b[j * 5 + i];
        #pragma unroll
        for (int g = 0; g < 5; ++g) {
            const float gv = -1.5f + 0.75f * (float)g;
            o += hatf(hj, gv) * s_w2[j * 5 + g];
        }
    }
    // stable softplus (matches jax.nn.softplus in fp32)
    const float sp = fmaxf(o, 0.0f) + log1pf(expf(-fabsf(o)));
    // cubic window on q = d/r
    const float q = sqrtf(d2) * INV_RADIUS;
    float win;
    if (q <= 0.5f) win = 2.0f / 3.0f - 4.0f * q * q + 4.0f * q * q * q;
    else           win = 4.0f / 3.0f - 4.0f * q + 4.0f * q * q
                         - (4.0f / 3.0f) * q * q * q;
    return sp * win;
}

__global__ __launch_bounds__(256) void meshfree_kan_kernel(
    const float* __restrict__ x, const float* __restrict__ nodes,
    const float* __restrict__ w,
    const float* __restrict__ w1a, const float* __restrict__ w1b,
    const float* __restrict__ w2,
    float* __restrict__ out, int M, int N)
{
    const int t = threadIdx.x;
    const int lane = t & 63, wave = t >> 6;

    __shared__ float s_w1a[40], s_w1b[40], s_w2[40];
    __shared__ int s_list[4][CAP];

    if (t < 40)       s_w1a[t]      = w1a[t];
    else if (t < 80)  s_w1b[t - 40] = w1b[t - 40];
    else if (t < 120) s_w2[t - 80]  = w2[t - 80];
    __syncthreads();   // ONLY barrier in the kernel; waves independent after this

    const int m = blockIdx.x * 4 + wave;
    if (m >= M) return;

    const float2* __restrict__ nodes2 = (const float2*)nodes;
    const float2 xm = ((const float2*)x)[m];
    const float x0 = xm.x, x1 = xm.y;
    int* __restrict__ myl = s_list[wave];

    float s1 = 0.0f, s2 = 0.0f;
    int cnt = 0;   // wave-uniform register compaction counter (no atomics)

    // ---- scan: 64 nodes/wave/iter, coalesced float2, ballot-compaction ----
    for (int base = 0; base < N; base += 512) {
        float2 nd[8];
        #pragma unroll
        for (int k = 0; k < 8; ++k) {
            const int n = base + (k << 6) + lane;
            nd[k] = (n < N) ? nodes2[n] : make_float2(1e15f, 1e15f);
        }
        #pragma unroll
        for (int k = 0; k < 8; ++k) {
            const int n = base + (k << 6) + lane;
            const float dx = x0 - nd[k].x;
            const float dy = x1 - nd[k].y;
            const float d2 = fmaf(dx, dx, dy * dy);
            const bool active = (d2 <= R2);   // n>=N padded to 1e15 -> inactive
            const unsigned long long mask = __ballot(active);
            if (mask) {                       // wave-uniform
                const int c = __popcll(mask);
                if (cnt + c > CAP) {          // cold: drain and reset (never
                    __threadfence_block();    //  taken on uniform data)
                    for (int i = lane; i < cnt; i += 64) {
                        const int nn = myl[i];
                        const float2 p = nodes2[nn];
                        const float ddx = x0 - p.x, ddy = x1 - p.y;
                        const float dd2 = fmaf(ddx, ddx, ddy * ddy);
                        const float pw = kan_phi(ddx, ddy, dd2,
                                                 s_w1a, s_w1b, s_w2);
                        s1 += pw;
                        s2 += pw * w[nn];
                    }
                    cnt = 0;
                }
                if (active)
                    myl[cnt + __popcll(mask & ((1ull << lane) - 1))] = n;
                cnt += c;
            }
        }
    }

    // ---- drain: one wave-pass of the heavy KAN over ~23 compacted pairs ----
    __threadfence_block();   // order ds_write -> ds_read within the wave
    for (int i = lane; i < cnt; i += 64) {
        const int n = myl[i];
        const float2 p = nodes2[n];          // L1-hot
        const float dx = x0 - p.x, dy = x1 - p.y;
        const float d2 = fmaf(dx, dx, dy * dy);
        const float pw = kan_phi(dx, dy, d2, s_w1a, s_w1b, s_w2);
        s1 += pw;
        s2 += pw * w[n];
    }

    // ---- in-wave butterfly reduction: all lanes end with the totals ----
    #pragma unroll
    for (int off = 32; off; off >>= 1) {
        s1 += __shfl_xor(s1, off);
        s2 += __shfl_xor(s2, off);
    }
    const float phi_sum = s1;

    if (phi_sum < 1e-14f) {
        // ---- orphan: exp-weighted 8-NN fallback (per-wave, recomputes d2;
        //      probability ~e^-23 per row with uniform data) ----
        // Keys order by d^2 (monotone in d); all d2 > R2 > 0 here so key > 0.
        const float alpha = (float)(20.0 / 0.06);
        unsigned long long last = 0ull;
        float accw = 0.0f, accwv = 0.0f;
        for (int sel = 0; sel < 8; ++sel) {
            unsigned long long best = ~0ull;
            for (int n = lane; n < N; n += 64) {
                const float2 p = nodes2[n];
                const float dx = x0 - p.x, dy = x1 - p.y;
                const float d2 = fmaf(dx, dx, dy * dy);
                const unsigned long long key =
                    ((unsigned long long)__float_as_uint(d2) << 32) |
                    (unsigned)n;
                if (key > last && key < best) best = key;
            }
            #pragma unroll
            for (int off = 32; off; off >>= 1) {
                const unsigned lo = (unsigned)best;
                const unsigned hi = (unsigned)(best >> 32);
                const unsigned olo = __shfl_xor(lo, off);
                const unsigned ohi = __shfl_xor(hi, off);
                const unsigned long long other =
                    ((unsigned long long)ohi << 32) | olo;
                if (other < best) best = other;
            }
            last = best;
            const float dk = sqrtf(__uint_as_float((unsigned)(best >> 32)));
            const int idx = (int)(best & 0xffffffffu);
            const float wk = expf(-alpha * dk);
            accw += wk;
            accwv += wk * w[idx];
        }
        if (lane == 0) out[m] = accwv / (accw + 1e-18f);
    } else {
        if (lane == 0) out[m] = s2 / (phi_sum + 1e-12f);
    }
}

extern "C" void kernel_launch(void* const* d_in, const int* in_sizes, int n_in,
                              void* d_out, int out_size, void* d_ws, size_t ws_size,
                              hipStream_t stream) {
    const float* x     = (const float*)d_in[0];
    const float* nodes = (const float*)d_in[1];
    const float* w     = (const float*)d_in[2];
    const float* w1a   = (const float*)d_in[3];
    const float* w1b   = (const float*)d_in[4];
    const float* w2    = (const float*)d_in[5];
    const int M = in_sizes[0] / 2;
    const int N = in_sizes[1] / 2;
    float* out = (float*)d_out;
    meshfree_kan_kernel<<<dim3((M + 3) / 4), dim3(256), 0, stream>>>(
        x, nodes, w, w1a, w1b, w2, out, M, N);
}

// Round 3
// 69.269 us; speedup vs baseline: 1.1042x; 1.0031x over previous
//
#include <hip/hip_runtime.h>
#include <math.h>

// MeshfreeKANNet: out[m] = sum_n phi(m,n) * w[n]
//   phi = windowed+normalized softplus(KAN(diff/radius)), cubic window radius 0.06
//   orphan rows (phi_sum < 1e-14) fall back to exp-weighted 8-NN.
//
// R5: latency-overlap restructure. R3/R4 post-mortem: dur 76.5->69.5 (kernel
// residual ~36->~29 us) -- still ~10x the instruction floor. Theory: the timed
// iteration runs right after a 256 MiB poison fill (83% HBM); its L2/L3
// writeback drain inflates every cold serial-dependent load (x[m], weights
// behind the staging barrier, first nodes lines) to ~us each, and 2
// barrier-coupled blocks/CU can't overlap the stalls.
// Changes:
//  - ONE WAVE PER BLOCK (64 thr), grid = M: 8 fully independent waves/CU,
//    zero barriers anywhere -> cold-miss stalls overlap across waves.
//  - Weights read directly via uniform-index global loads (compile to s_load
//    through the scalar K$): no LDS staging, weights off the critical path
//    (only the ~23-pair drain touches them).
//  - Full-chunk prefetch: all 32 strided float2 node loads issued before any
//    use -> one latency exposure per 2048-node chunk instead of four.
//  - Compaction CAP = chunk size (2048): overflow impossible, drain once per
//    chunk -> kan_phi instantiated ONCE (was 8x inlined in the scan).

#define RADIUS 0.06f
#define INV_RADIUS (1.0f / 0.06f)
#define R2 (0.06f * 0.06f)
#define INV_H (4.0f / 3.0f)   // 1/h, h = 0.75
#define CHUNK 2048            // nodes per scan pass; also compaction capacity

__device__ __forceinline__ float hatf(float x, float g) {
    return fmaxf(1.0f - fabsf(x - g) * INV_H, 0.0f);
}

// softplus(KAN(dx/r, dy/r)) * cubic_window(sqrt(d2)/r)
// Weights read through uniform-index global loads (scalar K$, L1-hot fast).
__device__ __forceinline__ float kan_phi(float dx, float dy, float d2,
                                         const float* __restrict__ w1a,
                                         const float* __restrict__ w1b,
                                         const float* __restrict__ w2) {
    const float u = dx * INV_RADIUS;
    const float v = dy * INV_RADIUS;
    float b0[5], b1[5];
    #pragma unroll
    for (int i = 0; i < 5; ++i) {
        const float g = -1.5f + 0.75f * (float)i;
        b0[i] = hatf(u, g);
        b1[i] = hatf(v, g);
    }
    float o = 0.0f;
    #pragma unroll
    for (int j = 0; j < 8; ++j) {
        float hj = 0.0f;
        #pragma unroll
        for (int i = 0; i < 5; ++i)
            hj += b0[i] * w1a[j * 5 + i] + b1[i] * w1b[j * 5 + i];
        #pragma unroll
        for (int g = 0; g < 5; ++g) {
            const float gv = -1.5f + 0.75f * (float)g;
            o += hatf(hj, gv) * w2[j * 5 + g];
        }
    }
    // stable softplus (matches jax.nn.softplus in fp32)
    const float sp = fmaxf(o, 0.0f) + log1pf(expf(-fabsf(o)));
    // cubic window on q = d/r
    const float q = sqrtf(d2) * INV_RADIUS;
    float win;
    if (q <= 0.5f) win = 2.0f / 3.0f - 4.0f * q * q + 4.0f * q * q * q;
    else           win = 4.0f / 3.0f - 4.0f * q + 4.0f * q * q
                         - (4.0f / 3.0f) * q * q * q;
    return sp * win;
}

__global__ __launch_bounds__(64) void meshfree_kan_kernel(
    const float* __restrict__ x, const float* __restrict__ nodes,
    const float* __restrict__ w,
    const float* __restrict__ w1a, const float* __restrict__ w1b,
    const float* __restrict__ w2,
    float* __restrict__ out, int M, int N)
{
    const int m = blockIdx.x;
    if (m >= M) return;
    const int lane = threadIdx.x;   // 0..63, one wave per block

    __shared__ int s_idx[CHUNK];    // 8 KB; 8 blocks/CU -> 64 KB of 160 KB

    const float2* __restrict__ nodes2 = (const float2*)nodes;
    const float2 xm = ((const float2*)x)[m];
    const float x0 = xm.x, x1 = xm.y;

    float s1 = 0.0f, s2 = 0.0f;

    for (int base = 0; base < N; base += CHUNK) {
        // ---- full-chunk prefetch: 32 strided float2 loads all in flight ----
        float2 nd[32];
        #pragma unroll
        for (int k = 0; k < 32; ++k) {
            const int n = base + (k << 6) + lane;
            nd[k] = (n < N) ? nodes2[n] : make_float2(1e15f, 1e15f);
        }
        // ---- ballot-compaction of active indices (no atomics, no branch
        //      to a heavy body; overflow impossible: <= CHUNK entries) ----
        int cnt = 0;
        #pragma unroll
        for (int k = 0; k < 32; ++k) {
            const int n = base + (k << 6) + lane;
            const float dx = x0 - nd[k].x;
            const float dy = x1 - nd[k].y;
            const float d2 = fmaf(dx, dx, dy * dy);
            const bool active = (d2 <= R2);   // padded lanes: 1e15 -> inactive
            const unsigned long long mask = __ballot(active);
            if (mask) {                       // wave-uniform
                if (active)
                    s_idx[cnt + __popcll(mask & ((1ull << lane) - 1))] = n;
                cnt += __popcll(mask);
            }
        }
        __threadfence_block();   // order ds_write -> ds_read within the wave
        // ---- drain: one wave-pass of the heavy KAN over ~23 pairs ----
        for (int i = lane; i < cnt; i += 64) {
            const int n = s_idx[i];
            const float2 p = nodes2[n];       // L1-hot (just streamed)
            const float dx = x0 - p.x, dy = x1 - p.y;
            const float d2 = fmaf(dx, dx, dy * dy);
            const float pw = kan_phi(dx, dy, d2, w1a, w1b, w2);
            s1 += pw;
            s2 += pw * w[n];
        }
    }

    // ---- in-wave butterfly reduction: all lanes end with the totals ----
    #pragma unroll
    for (int off = 32; off; off >>= 1) {
        s1 += __shfl_xor(s1, off);
        s2 += __shfl_xor(s2, off);
    }
    const float phi_sum = s1;

    if (phi_sum < 1e-14f) {
        // ---- orphan: exp-weighted 8-NN fallback (rescan; probability ~e^-23
        //      per row with uniform data, but must be correct) ----
        // Keys order by d^2 (monotone in d); all d2 > R2 > 0 here so key > 0.
        const float alpha = (float)(20.0 / 0.06);
        unsigned long long last = 0ull;
        float accw = 0.0f, accwv = 0.0f;
        for (int sel = 0; sel < 8; ++sel) {
            unsigned long long best = ~0ull;
            for (int n = lane; n < N; n += 64) {
                const float2 p = nodes2[n];
                const float dx = x0 - p.x, dy = x1 - p.y;
                const float d2 = fmaf(dx, dx, dy * dy);
                const unsigned long long key =
                    ((unsigned long long)__float_as_uint(d2) << 32) |
                    (unsigned)n;
                if (key > last && key < best) best = key;
            }
            #pragma unroll
            for (int off = 32; off; off >>= 1) {
                const unsigned lo = (unsigned)best;
                const unsigned hi = (unsigned)(best >> 32);
                const unsigned olo = __shfl_xor(lo, off);
                const unsigned ohi = __shfl_xor(hi, off);
                const unsigned long long other =
                    ((unsigned long long)ohi << 32) | olo;
                if (other < best) best = other;
            }
            last = best;
            const float dk = sqrtf(__uint_as_float((unsigned)(best >> 32)));
            const int idx = (int)(best & 0xffffffffu);
            const float wk = expf(-alpha * dk);
            accw += wk;
            accwv += wk * w[idx];
        }
        if (lane == 0) out[m] = accwv / (accw + 1e-18f);
    } else {
        if (lane == 0) out[m] = s2 / (phi_sum + 1e-12f);
    }
}

extern "C" void kernel_launch(void* const* d_in, const int* in_sizes, int n_in,
                              void* d_out, int out_size, void* d_ws, size_t ws_size,
                              hipStream_t stream) {
    const float* x     = (const float*)d_in[0];
    const float* nodes = (const float*)d_in[1];
    const float* w     = (const float*)d_in[2];
    const float* w1a   = (const float*)d_in[3];
    const float* w1b   = (const float*)d_in[4];
    const float* w2    = (const float*)d_in[5];
    const int M = in_sizes[0] / 2;
    const int N = in_sizes[1] / 2;
    float* out = (float*)d_out;
    meshfree_kan_kernel<<<dim3(M), dim3(64), 0, stream>>>(
        x, nodes, w, w1a, w1b, w2, out, M, N);
}